// Round 8
// baseline (176.229 us; speedup 1.0000x reference)
//
#include <hip/hip_runtime.h>
#include <math.h>

typedef unsigned char u8;
typedef __attribute__((ext_vector_type(4))) float floatx4;

#define B_ROWS 4096
#define D_DIM  256
#define C_CLS  20000
#define C_PAD  20096      // 157 tiles * 128
#define NTILE  157
#define NSPLIT 32
#define TAIL_BLOCKS 64

#define SC  43.280851227f   // 30 * log2(e)
#define M9  12.984255369f   // 9 * log2(e)

// ---- RNE f32 -> OCP e4m3fn (|v| <= 1 here; handles subnormals) ----
__device__ __forceinline__ u8 f32_to_e4m3(float v) {
  unsigned u = __float_as_uint(v);
  unsigned s = (u >> 24) & 0x80u;
  float a = fabsf(v);
  if (a < 0.0009765625f) return (u8)s;           // < 2^-10 -> rounds to 0
  unsigned ua = __float_as_uint(a);
  int ex = (int)(ua >> 23);
  if (ex < 121) ex = 121;                        // subnormal regime: step 2^-9
  float inv_step = __uint_as_float((unsigned)(257 - ex) << 23);  // 2^(3-e)
  float stepf    = __uint_as_float((unsigned)(ex - 3) << 23);    // 2^(e-3)
  float r = rintf(a * inv_step) * stepf;         // RNE to 3-bit mantissa grid
  unsigned code;
  if (r == 0.0f) code = 0;
  else {
    unsigned ur = __float_as_uint(r);
    int er = (int)(ur >> 23) - 127;
    if (er < -6) code = (unsigned)(r * 512.0f);  // subnormal: m * 2^-9
    else code = ((unsigned)(er + 7) << 3) | ((ur >> 20) & 7u);
  }
  return (u8)(s | code);
}

// ---- fused: normalize embeddings (f32+fp8) + label cosine + bucket; weights (fp8) ----
__global__ void normalize_all(const float* __restrict__ emb, const float* __restrict__ wgt,
                              const int* __restrict__ labels,
                              float* __restrict__ En, u8* __restrict__ E8,
                              u8* __restrict__ W8, float* __restrict__ lcos,
                              int* __restrict__ cnt_i, int* __restrict__ members) {
  const int r = blockIdx.x * 4 + (threadIdx.x >> 6);
  const int lane = threadIdx.x & 63;
  if (r < B_ROWS) {
    float4 v = ((const float4*)(emb + (size_t)r * D_DIM))[lane];
    float ss = v.x * v.x + v.y * v.y + v.z * v.z + v.w * v.w;
    for (int m = 1; m < 64; m <<= 1) ss += __shfl_xor(ss, m);
    float k = 1.0f / sqrtf(ss);
    v.x *= k; v.y *= k; v.z *= k; v.w *= k;
    ((float4*)(En + (size_t)r * D_DIM))[lane] = v;
    uchar4 c;
    c.x = f32_to_e4m3(v.x); c.y = f32_to_e4m3(v.y);
    c.z = f32_to_e4m3(v.z); c.w = f32_to_e4m3(v.w);
    ((uchar4*)(E8 + (size_t)r * D_DIM))[lane] = c;
    // label cosine in f32 (exact margin/label terms later)
    int lab = labels[r];
    float4 wv = ((const float4*)(wgt + (size_t)lab * D_DIM))[lane];
    float dot = v.x * wv.x + v.y * wv.y + v.z * wv.z + v.w * wv.w;
    float ws = wv.x * wv.x + wv.y * wv.y + wv.z * wv.z + wv.w * wv.w;
    for (int m = 1; m < 64; m <<= 1) {
      dot += __shfl_xor(dot, m);
      ws += __shfl_xor(ws, m);
    }
    if (lane == 0) {
      lcos[r] = dot / sqrtf(ws);
      int p = atomicAdd(&cnt_i[lab], 1);
      if (p < 16) members[lab * 16 + p] = r;
    }
  } else {
    int wr_ = r - B_ROWS;
    if (wr_ >= C_CLS) {
      uchar4 z = {0, 0, 0, 0};
      ((uchar4*)(W8 + (size_t)wr_ * D_DIM))[lane] = z;
      return;
    }
    float4 v = ((const float4*)(wgt + (size_t)wr_ * D_DIM))[lane];
    float ss = v.x * v.x + v.y * v.y + v.z * v.z + v.w * v.w;
    for (int m = 1; m < 64; m <<= 1) ss += __shfl_xor(ss, m);
    float k = 1.0f / sqrtf(ss);
    uchar4 c;
    c.x = f32_to_e4m3(v.x * k); c.y = f32_to_e4m3(v.y * k);
    c.z = f32_to_e4m3(v.z * k); c.w = f32_to_e4m3(v.w * k);
    ((uchar4*)(W8 + (size_t)wr_ * D_DIM))[lane] = c;
  }
}

// ---- fp8 cosine GEMM + exp-sum; NO LDS, NO barriers in the K-loop ----
// grid (16 row-tiles, 32 splits), 256 thr = 4 row-waves of 64 rows x 128 cols.
// B fragments load global->VGPR; compiler pipelines with fine-grained vmcnt.
__global__ __launch_bounds__(256, 2) void gemm_softmax(
    const u8* __restrict__ E8, const u8* __restrict__ W8,
    float* __restrict__ row_S) {
  const int tid = threadIdx.x;
  const int lane = tid & 63, w = tid >> 6;
  const int quad = lane >> 4, c16 = lane & 15;
  const int rt = blockIdx.x, sp = blockIdx.y;
  const int wr = w * 64;   // 4 waves x 64 rows = 256 rows

  // A fragments direct from global (one-time, 64 VGPRs)
  long a[4][8];
#pragma unroll
  for (int mt = 0; mt < 4; ++mt) {
    const u8* rp = E8 + ((size_t)(rt * 256 + wr + mt * 16 + c16)) * 256 + quad * 8;
#pragma unroll
    for (int kt = 0; kt < 8; ++kt)
      a[mt][kt] = *(const long*)(rp + kt * 32);
  }

  float run_s[4][4] = {};
  for (int t = sp; t < NTILE; t += NSPLIT) {
    // this wave's B base for the tile: row (nt*16 + c16), k-bytes quad*8 + kt*32
    const u8* wbase = W8 + (size_t)t * 32768 + c16 * 256 + quad * 8;
#pragma unroll
    for (int nt = 0; nt < 8; ++nt) {
      const u8* bp = wbase + nt * 4096;
      long b[8];
#pragma unroll
      for (int kt = 0; kt < 8; ++kt)
        b[kt] = *(const long*)(bp + kt * 32);
      floatx4 acc[4] = {};
#pragma unroll
      for (int kt = 0; kt < 8; ++kt)
#pragma unroll
        for (int mt = 0; mt < 4; ++mt)
          acc[mt] = __builtin_amdgcn_mfma_f32_16x16x32_fp8_fp8(a[mt][kt], b[kt], acc[mt], 0, 0, 0);
#pragma unroll
      for (int mt = 0; mt < 4; ++mt)
#pragma unroll
        for (int rg = 0; rg < 4; ++rg)
          run_s[mt][rg] += __builtin_amdgcn_exp2f(fmaf(SC, acc[mt][rg], -SC));
    }
  }
  // reduce across 16 column lanes, one atomic per row per wave
#pragma unroll
  for (int mt = 0; mt < 4; ++mt)
#pragma unroll
    for (int rg = 0; rg < 4; ++rg) {
      float s = run_s[mt][rg];
      s += __shfl_xor(s, 1);
      s += __shfl_xor(s, 2);
      s += __shfl_xor(s, 4);
      s += __shfl_xor(s, 8);
      if (c16 == 0)
        atomicAdd(&row_S[rt * 256 + wr + mt * 16 + quad * 4 + rg], s);
    }
}

// ---- tail: intra loss (closed form, wave-per-class) + AM row terms,
//      block-level LDS reduction -> 3 atomics/block, ticket combine ----
__global__ __launch_bounds__(1024) void tail(
    const int* __restrict__ cnt_i, const int* __restrict__ members,
    const float* __restrict__ En, const float* __restrict__ row_S,
    const float* __restrict__ lcos, float* __restrict__ pgnv,
    float* __restrict__ out) {
  __shared__ float red[1024];
  const int t = threadIdx.x, blk = blockIdx.x;
  const int gtid = blk * 1024 + t;
  const int lane = t & 63;
  const int gw = gtid >> 6;   // global wave id, 0..1023

  // --- intra: each wave scans classes gw, gw+1024, ... (closed form) ---
  float pg = 0.0f, nv = 0.0f;
  for (int c = gw; c < C_CLS; c += 1024) {
    int m = cnt_i[c];                 // same addr across wave -> broadcast
    if (m < 2) continue;
    if (m > 16) m = 16;
    float4 S = {0.0f, 0.0f, 0.0f, 0.0f};
    for (int r = 0; r < m; ++r) {
      int row = members[c * 16 + r];
      float4 v = ((const float4*)(En + (size_t)row * D_DIM))[lane];
      S.x += v.x; S.y += v.y; S.z += v.z; S.w += v.w;
    }
    float ss = S.x * S.x + S.y * S.y + S.z * S.z + S.w * S.w;
    for (int k = 1; k < 64; k <<= 1) ss += __shfl_xor(ss, k);
    if (lane == 0) {
      // sum_{r<s}(1 - e_r.e_s) = C(m,2) - (|sum e|^2 - m)/2  (unit-norm rows)
      float fm = (float)m;
      float np = 0.5f * fm * (fm - 1.0f);
      float dsum = np - 0.5f * (ss - fm);
      pg += fmaxf(dsum / np - 0.5f, 0.0f);
      nv += 1.0f;
    }
  }

  // --- AM: thread-per-row (65536 threads cover 4096 rows) ---
  const float padc = 96.0f * __builtin_amdgcn_exp2f(-SC);  // pad classes: cos==0 exactly
  float nlp = 0.0f;
  for (int r = gtid; r < B_ROWS; r += TAIL_BLOCKS * 1024) {
    float c = lcos[r];
    float S = row_S[r] - padc
            + __builtin_amdgcn_exp2f(fmaf(SC, c, -SC - M9))   // margined label term
            - __builtin_amdgcn_exp2f(fmaf(SC, c, -SC));       // remove unmargined label term
    nlp += 30.0f + logf(S) - fmaf(30.0f, c, -9.0f);
  }

  // --- block reduce (pg, nv, nlp) -> 3 atomics per block ---
  float bsum[3];
  float vals[3] = {pg, nv, nlp};
#pragma unroll
  for (int q = 0; q < 3; ++q) {
    red[t] = vals[q];
    __syncthreads();
    for (int s = 512; s > 0; s >>= 1) {
      if (t < s) red[t] += red[t + s];
      __syncthreads();
    }
    bsum[q] = red[0];
    __syncthreads();
  }
  if (t == 0) {
    atomicAdd(&pgnv[0], bsum[0]);
    atomicAdd(&pgnv[1], bsum[1]);
    atomicAdd(&pgnv[2], bsum[2]);
    __threadfence();
    unsigned ticket = atomicAdd((unsigned*)&pgnv[3], 1u);
    if (ticket == TAIL_BLOCKS - 1) {   // last block: all adds device-visible
      float pgT = atomicAdd(&pgnv[0], 0.0f);
      float nvT = atomicAdd(&pgnv[1], 0.0f);
      float nlT = atomicAdd(&pgnv[2], 0.0f);
      float am = nlT * (1.0f / (float)B_ROWS);
      float intra = (nvT > 0.0f) ? (pgT / nvT) : 0.0f;
      out[0] = am + 0.1f * intra;
      out[1] = am;
      out[2] = intra;
    }
  }
}

extern "C" void kernel_launch(void* const* d_in, const int* in_sizes, int n_in,
                              void* d_out, int out_size, void* d_ws, size_t ws_size,
                              hipStream_t stream) {
  const float* emb = (const float*)d_in[0];
  const int* labels = (const int*)d_in[1];
  const float* weight = (const float*)d_in[2];
  float* out = (float*)d_out;
  char* ws = (char*)d_ws;

  float* En      = (float*)(ws);               // 4,194,304
  u8*    E8      = (u8*)(ws + 4194304);        // 1,048,576 -> 5,242,880
  u8*    W8      = (u8*)(ws + 5242880);        // 5,144,576 -> 10,387,456
  float* row_S   = (float*)(ws + 10387456);    //    16,384 -> 10,403,840
  int*   cnt_i   = (int*)(ws + 10403840);      //    80,000 -> 10,483,840
  float* pgnv    = (float*)(ws + 10483840);    //        16 -> 10,483,856
  float* lcos    = (float*)(ws + 10483856);    //    16,384 -> 10,500,240
  int*   members = (int*)(ws + 10500240);      // 1,280,000 -> 11,780,240

  hipMemsetAsync(ws + 10387456, 0, 96400, stream);  // row_S + cnt_i + pgnv(+ticket)
  normalize_all<<<(B_ROWS + C_PAD) / 4, 256, 0, stream>>>(emb, weight, labels, En, E8, W8,
                                                          lcos, cnt_i, members);
  gemm_softmax<<<dim3(16, NSPLIT), 256, 0, stream>>>(E8, W8, row_S);
  tail<<<TAIL_BLOCKS, 1024, 0, stream>>>(cnt_i, members, En, row_S, lcos, pgnv, out);
}

// Round 9
// 150.351 us; speedup vs baseline: 1.1721x; 1.1721x over previous
//
#include <hip/hip_runtime.h>
#include <math.h>

typedef unsigned char u8;
typedef __attribute__((ext_vector_type(4))) float floatx4;

#define B_ROWS 4096
#define D_DIM  256
#define C_CLS  20000
#define C_PAD  20096      // 157 tiles * 128
#define NTILE  157
#define NSPLIT 32
#define TAIL_BLOCKS 64

#define SC  43.280851227f   // 30 * log2(e)
#define M9  12.984255369f   // 9 * log2(e)

// ---- RNE f32 -> OCP e4m3fn (|v| <= 1 here; handles subnormals) ----
__device__ __forceinline__ u8 f32_to_e4m3(float v) {
  unsigned u = __float_as_uint(v);
  unsigned s = (u >> 24) & 0x80u;
  float a = fabsf(v);
  if (a < 0.0009765625f) return (u8)s;           // < 2^-10 -> rounds to 0
  unsigned ua = __float_as_uint(a);
  int ex = (int)(ua >> 23);
  if (ex < 121) ex = 121;                        // subnormal regime: step 2^-9
  float inv_step = __uint_as_float((unsigned)(257 - ex) << 23);  // 2^(3-e)
  float stepf    = __uint_as_float((unsigned)(ex - 3) << 23);    // 2^(e-3)
  float r = rintf(a * inv_step) * stepf;         // RNE to 3-bit mantissa grid
  unsigned code;
  if (r == 0.0f) code = 0;
  else {
    unsigned ur = __float_as_uint(r);
    int er = (int)(ur >> 23) - 127;
    if (er < -6) code = (unsigned)(r * 512.0f);  // subnormal: m * 2^-9
    else code = ((unsigned)(er + 7) << 3) | ((ur >> 20) & 7u);
  }
  return (u8)(s | code);
}

// ---- fused: normalize embeddings (f32+fp8) + label cosine + bucket; weights (fp8) ----
__global__ void normalize_all(const float* __restrict__ emb, const float* __restrict__ wgt,
                              const int* __restrict__ labels,
                              float* __restrict__ En, u8* __restrict__ E8,
                              u8* __restrict__ W8, float* __restrict__ lcos,
                              int* __restrict__ cnt_i, int* __restrict__ members) {
  const int r = blockIdx.x * 4 + (threadIdx.x >> 6);
  const int lane = threadIdx.x & 63;
  if (r < B_ROWS) {
    float4 v = ((const float4*)(emb + (size_t)r * D_DIM))[lane];
    float ss = v.x * v.x + v.y * v.y + v.z * v.z + v.w * v.w;
    for (int m = 1; m < 64; m <<= 1) ss += __shfl_xor(ss, m);
    float k = 1.0f / sqrtf(ss);
    v.x *= k; v.y *= k; v.z *= k; v.w *= k;
    ((float4*)(En + (size_t)r * D_DIM))[lane] = v;
    uchar4 c;
    c.x = f32_to_e4m3(v.x); c.y = f32_to_e4m3(v.y);
    c.z = f32_to_e4m3(v.z); c.w = f32_to_e4m3(v.w);
    ((uchar4*)(E8 + (size_t)r * D_DIM))[lane] = c;
    // label cosine in f32 (exact margin/label terms later)
    int lab = labels[r];
    float4 wv = ((const float4*)(wgt + (size_t)lab * D_DIM))[lane];
    float dot = v.x * wv.x + v.y * wv.y + v.z * wv.z + v.w * wv.w;
    float ws = wv.x * wv.x + wv.y * wv.y + wv.z * wv.z + wv.w * wv.w;
    for (int m = 1; m < 64; m <<= 1) {
      dot += __shfl_xor(dot, m);
      ws += __shfl_xor(ws, m);
    }
    if (lane == 0) {
      lcos[r] = dot / sqrtf(ws);
      int p = atomicAdd(&cnt_i[lab], 1);
      if (p < 16) members[lab * 16 + p] = r;
    }
  } else {
    int wr_ = r - B_ROWS;
    if (wr_ >= C_CLS) {
      uchar4 z = {0, 0, 0, 0};
      ((uchar4*)(W8 + (size_t)wr_ * D_DIM))[lane] = z;
      return;
    }
    float4 v = ((const float4*)(wgt + (size_t)wr_ * D_DIM))[lane];
    float ss = v.x * v.x + v.y * v.y + v.z * v.z + v.w * v.w;
    for (int m = 1; m < 64; m <<= 1) ss += __shfl_xor(ss, m);
    float k = 1.0f / sqrtf(ss);
    uchar4 c;
    c.x = f32_to_e4m3(v.x * k); c.y = f32_to_e4m3(v.y * k);
    c.z = f32_to_e4m3(v.z * k); c.w = f32_to_e4m3(v.w * k);
    ((uchar4*)(W8 + (size_t)wr_ * D_DIM))[lane] = c;
  }
}

// ---- fp8 cosine GEMM + exp-sum; M=256/N=128, VGPR-roundtrip double buffer ----
// grid (16 row-tiles, 32 splits), 256 thr = 4 row-waves of 64 rows x 128 cols.
// Iter: issue global->VGPR loads of tile t+1 (vmcnt pending through MFMA phase),
// compute tile t from LDS (lgkmcnt only), then ds_write t+1, one barrier.
__global__ __launch_bounds__(256, 2) void gemm_softmax(
    const u8* __restrict__ E8, const u8* __restrict__ W8,
    float* __restrict__ row_S) {
  __shared__ char lds[65536];   // 2 x 32 KB
  const int tid = threadIdx.x;
  const int lane = tid & 63, w = tid >> 6;
  const int quad = lane >> 4, c16 = lane & 15;
  const int qh = quad >> 1, qb8 = (quad & 1) << 3;
  const int rt = blockIdx.x, sp = blockIdx.y;
  const int wr = w * 64;   // 4 waves x 64 rows = 256 rows

  // staging maps: thread tid loads granules f=i*256+tid (LINEAR, coalesced) and
  // ds_writes swizzled: row n=f>>4, slot (f&15)^(n&15). n&15 == tid>>4.
  const int ldsDstBase = ((tid >> 4) << 8) + (((tid & 15) ^ (tid >> 4)) << 4);
  uint4 st[8];
  auto loads = [&](int t) {
    const char* src = (const char*)W8 + (size_t)t * 32768 + tid * 16;
#pragma unroll
    for (int i = 0; i < 8; ++i)
      st[i] = *(const uint4*)(src + i * 4096);
  };
  auto writes = [&](int buf) {
    char* dst = lds + buf * 32768 + ldsDstBase;
#pragma unroll
    for (int i = 0; i < 8; ++i)
      *(uint4*)(dst + i * 4096) = st[i];
  };

  // A fragments direct from global (one-time, 64 VGPRs)
  long a[4][8];
#pragma unroll
  for (int mt = 0; mt < 4; ++mt) {
    const u8* rp = E8 + ((size_t)(rt * 256 + wr + mt * 16 + c16)) * 256 + quad * 8;
#pragma unroll
    for (int kt = 0; kt < 8; ++kt)
      a[mt][kt] = *(const long*)(rp + kt * 32);
  }

  // per-kt B read offsets within a row (16B chunk (2kt+qh)^c16, 8B half qb8)
  int o[8];
#pragma unroll
  for (int kt = 0; kt < 8; ++kt)
    o[kt] = ((((kt << 1) + qh) ^ c16) << 4) + qb8;

  // prologue: stage first tile
  loads(sp);
  writes(0);
  __syncthreads();

  float run_s[4][4] = {};
  int cur = 0;
  for (int t = sp; t < NTILE; t += NSPLIT) {
    int tn = t + NSPLIT;
    if (tn < NTILE) loads(tn);   // async; first use is the ds_write AFTER compute
    const char* bbase = lds + cur * 32768 + c16 * 256;
#pragma unroll
    for (int nt = 0; nt < 8; ++nt) {
      long b[8];
#pragma unroll
      for (int kt = 0; kt < 8; ++kt)
        b[kt] = *(const long*)(bbase + nt * 4096 + o[kt]);
      floatx4 acc[4] = {};
#pragma unroll
      for (int kt = 0; kt < 8; ++kt)
#pragma unroll
        for (int mt = 0; mt < 4; ++mt)
          acc[mt] = __builtin_amdgcn_mfma_f32_16x16x32_fp8_fp8(a[mt][kt], b[kt], acc[mt], 0, 0, 0);
#pragma unroll
      for (int mt = 0; mt < 4; ++mt)
#pragma unroll
        for (int rg = 0; rg < 4; ++rg)
          run_s[mt][rg] += __builtin_amdgcn_exp2f(fmaf(SC, acc[mt][rg], -SC));
    }
    if (tn < NTILE) writes(cur ^ 1);   // vmcnt wait lands here, after MFMA phase
    __syncthreads();
    cur ^= 1;
  }
  // reduce across 16 column lanes, one atomic per row per wave
#pragma unroll
  for (int mt = 0; mt < 4; ++mt)
#pragma unroll
    for (int rg = 0; rg < 4; ++rg) {
      float s = run_s[mt][rg];
      s += __shfl_xor(s, 1);
      s += __shfl_xor(s, 2);
      s += __shfl_xor(s, 4);
      s += __shfl_xor(s, 8);
      if (c16 == 0)
        atomicAdd(&row_S[rt * 256 + wr + mt * 16 + quad * 4 + rg], s);
    }
}

// ---- tail: intra loss (closed form, wave-per-class) + AM row terms,
//      block-level LDS reduction -> 3 atomics/block, ticket combine ----
__global__ __launch_bounds__(1024) void tail(
    const int* __restrict__ cnt_i, const int* __restrict__ members,
    const float* __restrict__ En, const float* __restrict__ row_S,
    const float* __restrict__ lcos, float* __restrict__ pgnv,
    float* __restrict__ out) {
  __shared__ float red[1024];
  const int t = threadIdx.x, blk = blockIdx.x;
  const int gtid = blk * 1024 + t;
  const int lane = t & 63;
  const int gw = gtid >> 6;   // global wave id, 0..1023

  // --- intra: each wave scans classes gw, gw+1024, ... (closed form) ---
  float pg = 0.0f, nv = 0.0f;
  for (int c = gw; c < C_CLS; c += 1024) {
    int m = cnt_i[c];                 // same addr across wave -> broadcast
    if (m < 2) continue;
    if (m > 16) m = 16;
    float4 S = {0.0f, 0.0f, 0.0f, 0.0f};
    for (int r = 0; r < m; ++r) {
      int row = members[c * 16 + r];
      float4 v = ((const float4*)(En + (size_t)row * D_DIM))[lane];
      S.x += v.x; S.y += v.y; S.z += v.z; S.w += v.w;
    }
    float ss = S.x * S.x + S.y * S.y + S.z * S.z + S.w * S.w;
    for (int k = 1; k < 64; k <<= 1) ss += __shfl_xor(ss, k);
    if (lane == 0) {
      // sum_{r<s}(1 - e_r.e_s) = C(m,2) - (|sum e|^2 - m)/2  (unit-norm rows)
      float fm = (float)m;
      float np = 0.5f * fm * (fm - 1.0f);
      float dsum = np - 0.5f * (ss - fm);
      pg += fmaxf(dsum / np - 0.5f, 0.0f);
      nv += 1.0f;
    }
  }

  // --- AM: thread-per-row (65536 threads cover 4096 rows) ---
  const float padc = 96.0f * __builtin_amdgcn_exp2f(-SC);  // pad classes: cos==0 exactly
  float nlp = 0.0f;
  for (int r = gtid; r < B_ROWS; r += TAIL_BLOCKS * 1024) {
    float c = lcos[r];
    float S = row_S[r] - padc
            + __builtin_amdgcn_exp2f(fmaf(SC, c, -SC - M9))   // margined label term
            - __builtin_amdgcn_exp2f(fmaf(SC, c, -SC));       // remove unmargined label term
    nlp += 30.0f + logf(S) - fmaf(30.0f, c, -9.0f);
  }

  // --- block reduce (pg, nv, nlp) -> 3 atomics per block ---
  float bsum[3];
  float vals[3] = {pg, nv, nlp};
#pragma unroll
  for (int q = 0; q < 3; ++q) {
    red[t] = vals[q];
    __syncthreads();
    for (int s = 512; s > 0; s >>= 1) {
      if (t < s) red[t] += red[t + s];
      __syncthreads();
    }
    bsum[q] = red[0];
    __syncthreads();
  }
  if (t == 0) {
    atomicAdd(&pgnv[0], bsum[0]);
    atomicAdd(&pgnv[1], bsum[1]);
    atomicAdd(&pgnv[2], bsum[2]);
    __threadfence();
    unsigned ticket = atomicAdd((unsigned*)&pgnv[3], 1u);
    if (ticket == TAIL_BLOCKS - 1) {   // last block: all adds device-visible
      float pgT = atomicAdd(&pgnv[0], 0.0f);
      float nvT = atomicAdd(&pgnv[1], 0.0f);
      float nlT = atomicAdd(&pgnv[2], 0.0f);
      float am = nlT * (1.0f / (float)B_ROWS);
      float intra = (nvT > 0.0f) ? (pgT / nvT) : 0.0f;
      out[0] = am + 0.1f * intra;
      out[1] = am;
      out[2] = intra;
    }
  }
}

extern "C" void kernel_launch(void* const* d_in, const int* in_sizes, int n_in,
                              void* d_out, int out_size, void* d_ws, size_t ws_size,
                              hipStream_t stream) {
  const float* emb = (const float*)d_in[0];
  const int* labels = (const int*)d_in[1];
  const float* weight = (const float*)d_in[2];
  float* out = (float*)d_out;
  char* ws = (char*)d_ws;

  float* En      = (float*)(ws);               // 4,194,304
  u8*    E8      = (u8*)(ws + 4194304);        // 1,048,576 -> 5,242,880
  u8*    W8      = (u8*)(ws + 5242880);        // 5,144,576 -> 10,387,456
  float* row_S   = (float*)(ws + 10387456);    //    16,384 -> 10,403,840
  int*   cnt_i   = (int*)(ws + 10403840);      //    80,000 -> 10,483,840
  float* pgnv    = (float*)(ws + 10483840);    //        16 -> 10,483,856
  float* lcos    = (float*)(ws + 10483856);    //    16,384 -> 10,500,240
  int*   members = (int*)(ws + 10500240);      // 1,280,000 -> 11,780,240

  hipMemsetAsync(ws + 10387456, 0, 96400, stream);  // row_S + cnt_i + pgnv(+ticket)
  normalize_all<<<(B_ROWS + C_PAD) / 4, 256, 0, stream>>>(emb, weight, labels, En, E8, W8,
                                                          lcos, cnt_i, members);
  gemm_softmax<<<dim3(16, NSPLIT), 256, 0, stream>>>(E8, W8, row_S);
  tail<<<TAIL_BLOCKS, 1024, 0, stream>>>(cnt_i, members, En, row_S, lcos, pgnv, out);
}

// Round 10
// 148.916 us; speedup vs baseline: 1.1834x; 1.0096x over previous
//
#include <hip/hip_runtime.h>
#include <math.h>

typedef unsigned char u8;
typedef __attribute__((ext_vector_type(4))) float floatx4;

#define B_ROWS 4096
#define D_DIM  256
#define C_CLS  20000
#define C_PAD  20096      // 157 tiles * 128
#define NTILE  157
#define NSPLIT 32
#define TAIL_BLOCKS 64

#define SC  43.280851227f   // 30 * log2(e)
#define M9  12.984255369f   // 9 * log2(e)

// ---- RNE f32 -> OCP e4m3fn (|v| <= 1 here; handles subnormals) ----
__device__ __forceinline__ u8 f32_to_e4m3(float v) {
  unsigned u = __float_as_uint(v);
  unsigned s = (u >> 24) & 0x80u;
  float a = fabsf(v);
  if (a < 0.0009765625f) return (u8)s;           // < 2^-10 -> rounds to 0
  unsigned ua = __float_as_uint(a);
  int ex = (int)(ua >> 23);
  if (ex < 121) ex = 121;                        // subnormal regime: step 2^-9
  float inv_step = __uint_as_float((unsigned)(257 - ex) << 23);  // 2^(3-e)
  float stepf    = __uint_as_float((unsigned)(ex - 3) << 23);    // 2^(e-3)
  float r = rintf(a * inv_step) * stepf;         // RNE to 3-bit mantissa grid
  unsigned code;
  if (r == 0.0f) code = 0;
  else {
    unsigned ur = __float_as_uint(r);
    int er = (int)(ur >> 23) - 127;
    if (er < -6) code = (unsigned)(r * 512.0f);  // subnormal: m * 2^-9
    else code = ((unsigned)(er + 7) << 3) | ((ur >> 20) & 7u);
  }
  return (u8)(s | code);
}

// ---- fused: normalize embeddings (f32+fp8) + label cosine + bucket; weights (fp8) ----
__global__ void normalize_all(const float* __restrict__ emb, const float* __restrict__ wgt,
                              const int* __restrict__ labels,
                              float* __restrict__ En, u8* __restrict__ E8,
                              u8* __restrict__ W8, float* __restrict__ lcos,
                              int* __restrict__ cnt_i, int* __restrict__ members) {
  const int r = blockIdx.x * 4 + (threadIdx.x >> 6);
  const int lane = threadIdx.x & 63;
  if (r < B_ROWS) {
    float4 v = ((const float4*)(emb + (size_t)r * D_DIM))[lane];
    float ss = v.x * v.x + v.y * v.y + v.z * v.z + v.w * v.w;
    for (int m = 1; m < 64; m <<= 1) ss += __shfl_xor(ss, m);
    float k = 1.0f / sqrtf(ss);
    v.x *= k; v.y *= k; v.z *= k; v.w *= k;
    ((float4*)(En + (size_t)r * D_DIM))[lane] = v;
    uchar4 c;
    c.x = f32_to_e4m3(v.x); c.y = f32_to_e4m3(v.y);
    c.z = f32_to_e4m3(v.z); c.w = f32_to_e4m3(v.w);
    ((uchar4*)(E8 + (size_t)r * D_DIM))[lane] = c;
    // label cosine in f32 (exact margin/label terms later)
    int lab = labels[r];
    float4 wv = ((const float4*)(wgt + (size_t)lab * D_DIM))[lane];
    float dot = v.x * wv.x + v.y * wv.y + v.z * wv.z + v.w * wv.w;
    float ws = wv.x * wv.x + wv.y * wv.y + wv.z * wv.z + wv.w * wv.w;
    for (int m = 1; m < 64; m <<= 1) {
      dot += __shfl_xor(dot, m);
      ws += __shfl_xor(ws, m);
    }
    if (lane == 0) {
      lcos[r] = dot / sqrtf(ws);
      int p = atomicAdd(&cnt_i[lab], 1);
      if (p < 16) members[lab * 16 + p] = r;
    }
  } else {
    int wr_ = r - B_ROWS;
    if (wr_ >= C_CLS) {
      uchar4 z = {0, 0, 0, 0};
      ((uchar4*)(W8 + (size_t)wr_ * D_DIM))[lane] = z;
      return;
    }
    float4 v = ((const float4*)(wgt + (size_t)wr_ * D_DIM))[lane];
    float ss = v.x * v.x + v.y * v.y + v.z * v.z + v.w * v.w;
    for (int m = 1; m < 64; m <<= 1) ss += __shfl_xor(ss, m);
    float k = 1.0f / sqrtf(ss);
    uchar4 c;
    c.x = f32_to_e4m3(v.x * k); c.y = f32_to_e4m3(v.y * k);
    c.z = f32_to_e4m3(v.z * k); c.w = f32_to_e4m3(v.w * k);
    ((uchar4*)(W8 + (size_t)wr_ * D_DIM))[lane] = c;
  }
}

// ---- fp8 cosine GEMM + exp-sum; M=256/N=128, VGPR-roundtrip double buffer ----
// grid (16 row-tiles, 32 splits), 256 thr = 4 row-waves of 64 rows x 128 cols.
// waves_per_eu pinned to (2,2): 256-VGPR budget so the 32-reg staged tile is
// NOT spilled to scratch (R9: compiler targeted 4 waves/EU -> 69 MB scratch).
__global__ __attribute__((amdgpu_flat_work_group_size(256, 256), amdgpu_waves_per_eu(2, 2)))
void gemm_softmax(
    const u8* __restrict__ E8, const u8* __restrict__ W8,
    float* __restrict__ row_S) {
  __shared__ char lds[65536];   // 2 x 32 KB
  const int tid = threadIdx.x;
  const int lane = tid & 63, w = tid >> 6;
  const int quad = lane >> 4, c16 = lane & 15;
  const int qh = quad >> 1, qb8 = (quad & 1) << 3;
  const int rt = blockIdx.x, sp = blockIdx.y;
  const int wr = w * 64;   // 4 waves x 64 rows = 256 rows

  // staging maps: thread tid loads granules f=i*256+tid (LINEAR, coalesced) and
  // ds_writes swizzled: row n=f>>4, slot (f&15)^(n&15). n&15 == tid>>4.
  const int ldsDstBase = ((tid >> 4) << 8) + (((tid & 15) ^ (tid >> 4)) << 4);
  uint4 st[8];
  auto loads = [&](int t) {
    const char* src = (const char*)W8 + (size_t)t * 32768 + tid * 16;
#pragma unroll
    for (int i = 0; i < 8; ++i)
      st[i] = *(const uint4*)(src + i * 4096);
  };
  auto writes = [&](int buf) {
    char* dst = lds + buf * 32768 + ldsDstBase;
#pragma unroll
    for (int i = 0; i < 8; ++i)
      *(uint4*)(dst + i * 4096) = st[i];
  };

  // A fragments direct from global (one-time, 64 VGPRs)
  long a[4][8];
#pragma unroll
  for (int mt = 0; mt < 4; ++mt) {
    const u8* rp = E8 + ((size_t)(rt * 256 + wr + mt * 16 + c16)) * 256 + quad * 8;
#pragma unroll
    for (int kt = 0; kt < 8; ++kt)
      a[mt][kt] = *(const long*)(rp + kt * 32);
  }

  // per-kt B read offsets within a row (16B chunk (2kt+qh)^c16, 8B half qb8)
  int o[8];
#pragma unroll
  for (int kt = 0; kt < 8; ++kt)
    o[kt] = ((((kt << 1) + qh) ^ c16) << 4) + qb8;

  // prologue: stage first tile
  loads(sp);
  writes(0);
  __syncthreads();

  float run_s[4][4] = {};
  int cur = 0;
  for (int t = sp; t < NTILE; t += NSPLIT) {
    int tn = t + NSPLIT;
    if (tn < NTILE) loads(tn);   // async; first use is the ds_write AFTER compute
    const char* bbase = lds + cur * 32768 + c16 * 256;
#pragma unroll
    for (int nt = 0; nt < 8; ++nt) {
      long b[8];
#pragma unroll
      for (int kt = 0; kt < 8; ++kt)
        b[kt] = *(const long*)(bbase + nt * 4096 + o[kt]);
      floatx4 acc[4] = {};
#pragma unroll
      for (int kt = 0; kt < 8; ++kt)
#pragma unroll
        for (int mt = 0; mt < 4; ++mt)
          acc[mt] = __builtin_amdgcn_mfma_f32_16x16x32_fp8_fp8(a[mt][kt], b[kt], acc[mt], 0, 0, 0);
#pragma unroll
      for (int mt = 0; mt < 4; ++mt)
#pragma unroll
        for (int rg = 0; rg < 4; ++rg)
          run_s[mt][rg] += __builtin_amdgcn_exp2f(fmaf(SC, acc[mt][rg], -SC));
    }
    if (tn < NTILE) writes(cur ^ 1);   // vmcnt wait lands here, after MFMA phase
    __syncthreads();
    cur ^= 1;
  }
  // reduce across 16 column lanes, one atomic per row per wave
#pragma unroll
  for (int mt = 0; mt < 4; ++mt)
#pragma unroll
    for (int rg = 0; rg < 4; ++rg) {
      float s = run_s[mt][rg];
      s += __shfl_xor(s, 1);
      s += __shfl_xor(s, 2);
      s += __shfl_xor(s, 4);
      s += __shfl_xor(s, 8);
      if (c16 == 0)
        atomicAdd(&row_S[rt * 256 + wr + mt * 16 + quad * 4 + rg], s);
    }
}

// ---- tail: intra loss (closed form, wave-per-class) + AM row terms,
//      block-level LDS reduction -> 3 atomics/block, ticket combine ----
__global__ __launch_bounds__(1024) void tail(
    const int* __restrict__ cnt_i, const int* __restrict__ members,
    const float* __restrict__ En, const float* __restrict__ row_S,
    const float* __restrict__ lcos, float* __restrict__ pgnv,
    float* __restrict__ out) {
  __shared__ float red[1024];
  const int t = threadIdx.x, blk = blockIdx.x;
  const int gtid = blk * 1024 + t;
  const int lane = t & 63;
  const int gw = gtid >> 6;   // global wave id, 0..1023

  // --- intra: each wave scans classes gw, gw+1024, ... (closed form) ---
  float pg = 0.0f, nv = 0.0f;
  for (int c = gw; c < C_CLS; c += 1024) {
    int m = cnt_i[c];                 // same addr across wave -> broadcast
    if (m < 2) continue;
    if (m > 16) m = 16;
    float4 S = {0.0f, 0.0f, 0.0f, 0.0f};
    for (int r = 0; r < m; ++r) {
      int row = members[c * 16 + r];
      float4 v = ((const float4*)(En + (size_t)row * D_DIM))[lane];
      S.x += v.x; S.y += v.y; S.z += v.z; S.w += v.w;
    }
    float ss = S.x * S.x + S.y * S.y + S.z * S.z + S.w * S.w;
    for (int k = 1; k < 64; k <<= 1) ss += __shfl_xor(ss, k);
    if (lane == 0) {
      // sum_{r<s}(1 - e_r.e_s) = C(m,2) - (|sum e|^2 - m)/2  (unit-norm rows)
      float fm = (float)m;
      float np = 0.5f * fm * (fm - 1.0f);
      float dsum = np - 0.5f * (ss - fm);
      pg += fmaxf(dsum / np - 0.5f, 0.0f);
      nv += 1.0f;
    }
  }

  // --- AM: thread-per-row (65536 threads cover 4096 rows) ---
  const float padc = 96.0f * __builtin_amdgcn_exp2f(-SC);  // pad classes: cos==0 exactly
  float nlp = 0.0f;
  for (int r = gtid; r < B_ROWS; r += TAIL_BLOCKS * 1024) {
    float c = lcos[r];
    float S = row_S[r] - padc
            + __builtin_amdgcn_exp2f(fmaf(SC, c, -SC - M9))   // margined label term
            - __builtin_amdgcn_exp2f(fmaf(SC, c, -SC));       // remove unmargined label term
    nlp += 30.0f + logf(S) - fmaf(30.0f, c, -9.0f);
  }

  // --- block reduce (pg, nv, nlp) -> 3 atomics per block ---
  float bsum[3];
  float vals[3] = {pg, nv, nlp};
#pragma unroll
  for (int q = 0; q < 3; ++q) {
    red[t] = vals[q];
    __syncthreads();
    for (int s = 512; s > 0; s >>= 1) {
      if (t < s) red[t] += red[t + s];
      __syncthreads();
    }
    bsum[q] = red[0];
    __syncthreads();
  }
  if (t == 0) {
    atomicAdd(&pgnv[0], bsum[0]);
    atomicAdd(&pgnv[1], bsum[1]);
    atomicAdd(&pgnv[2], bsum[2]);
    __threadfence();
    unsigned ticket = atomicAdd((unsigned*)&pgnv[3], 1u);
    if (ticket == TAIL_BLOCKS - 1) {   // last block: all adds device-visible
      float pgT = atomicAdd(&pgnv[0], 0.0f);
      float nvT = atomicAdd(&pgnv[1], 0.0f);
      float nlT = atomicAdd(&pgnv[2], 0.0f);
      float am = nlT * (1.0f / (float)B_ROWS);
      float intra = (nvT > 0.0f) ? (pgT / nvT) : 0.0f;
      out[0] = am + 0.1f * intra;
      out[1] = am;
      out[2] = intra;
    }
  }
}

extern "C" void kernel_launch(void* const* d_in, const int* in_sizes, int n_in,
                              void* d_out, int out_size, void* d_ws, size_t ws_size,
                              hipStream_t stream) {
  const float* emb = (const float*)d_in[0];
  const int* labels = (const int*)d_in[1];
  const float* weight = (const float*)d_in[2];
  float* out = (float*)d_out;
  char* ws = (char*)d_ws;

  float* En      = (float*)(ws);               // 4,194,304
  u8*    E8      = (u8*)(ws + 4194304);        // 1,048,576 -> 5,242,880
  u8*    W8      = (u8*)(ws + 5242880);        // 5,144,576 -> 10,387,456
  float* row_S   = (float*)(ws + 10387456);    //    16,384 -> 10,403,840
  int*   cnt_i   = (int*)(ws + 10403840);      //    80,000 -> 10,483,840
  float* pgnv    = (float*)(ws + 10483840);    //        16 -> 10,483,856
  float* lcos    = (float*)(ws + 10483856);    //    16,384 -> 10,500,240
  int*   members = (int*)(ws + 10500240);      // 1,280,000 -> 11,780,240

  hipMemsetAsync(ws + 10387456, 0, 96400, stream);  // row_S + cnt_i + pgnv(+ticket)
  normalize_all<<<(B_ROWS + C_PAD) / 4, 256, 0, stream>>>(emb, weight, labels, En, E8, W8,
                                                          lcos, cnt_i, members);
  gemm_softmax<<<dim3(16, NSPLIT), 256, 0, stream>>>(E8, W8, row_S);
  tail<<<TAIL_BLOCKS, 1024, 0, stream>>>(cnt_i, members, En, row_S, lcos, pgnv, out);
}

// Round 11
// 120.893 us; speedup vs baseline: 1.4577x; 1.2318x over previous
//
#include <hip/hip_runtime.h>
#include <math.h>

typedef unsigned char u8;
typedef __attribute__((ext_vector_type(4))) float floatx4;
typedef __attribute__((ext_vector_type(8))) int intx8;

#define B_ROWS 4096
#define D_DIM  256
#define C_CLS  20000
#define C_PAD  20096      // 157 tiles * 128
#define NTILE  157
#define NSPLIT 32
#define TAIL_BLOCKS 64

#define SC  43.280851227f   // 30 * log2(e)
#define M9  12.984255369f   // 9 * log2(e)
#define SCL1 0x7f7f7f7f     // e8m0 == 127 -> scale 2^0 = 1.0 (all bytes)

// ---- RNE f32 -> OCP e4m3fn (|v| <= 1 here; handles subnormals) ----
__device__ __forceinline__ u8 f32_to_e4m3(float v) {
  unsigned u = __float_as_uint(v);
  unsigned s = (u >> 24) & 0x80u;
  float a = fabsf(v);
  if (a < 0.0009765625f) return (u8)s;           // < 2^-10 -> rounds to 0
  unsigned ua = __float_as_uint(a);
  int ex = (int)(ua >> 23);
  if (ex < 121) ex = 121;                        // subnormal regime: step 2^-9
  float inv_step = __uint_as_float((unsigned)(257 - ex) << 23);  // 2^(3-e)
  float stepf    = __uint_as_float((unsigned)(ex - 3) << 23);    // 2^(e-3)
  float r = rintf(a * inv_step) * stepf;         // RNE to 3-bit mantissa grid
  unsigned code;
  if (r == 0.0f) code = 0;
  else {
    unsigned ur = __float_as_uint(r);
    int er = (int)(ur >> 23) - 127;
    if (er < -6) code = (unsigned)(r * 512.0f);  // subnormal: m * 2^-9
    else code = ((unsigned)(er + 7) << 3) | ((ur >> 20) & 7u);
  }
  return (u8)(s | code);
}

// ---- fused: normalize embeddings (f32+fp8) + label cosine + bucket; weights (fp8) ----
__global__ void normalize_all(const float* __restrict__ emb, const float* __restrict__ wgt,
                              const int* __restrict__ labels,
                              float* __restrict__ En, u8* __restrict__ E8,
                              u8* __restrict__ W8, float* __restrict__ lcos,
                              int* __restrict__ cnt_i, int* __restrict__ members) {
  const int r = blockIdx.x * 4 + (threadIdx.x >> 6);
  const int lane = threadIdx.x & 63;
  if (r < B_ROWS) {
    float4 v = ((const float4*)(emb + (size_t)r * D_DIM))[lane];
    float ss = v.x * v.x + v.y * v.y + v.z * v.z + v.w * v.w;
    for (int m = 1; m < 64; m <<= 1) ss += __shfl_xor(ss, m);
    float k = 1.0f / sqrtf(ss);
    v.x *= k; v.y *= k; v.z *= k; v.w *= k;
    ((float4*)(En + (size_t)r * D_DIM))[lane] = v;
    uchar4 c;
    c.x = f32_to_e4m3(v.x); c.y = f32_to_e4m3(v.y);
    c.z = f32_to_e4m3(v.z); c.w = f32_to_e4m3(v.w);
    ((uchar4*)(E8 + (size_t)r * D_DIM))[lane] = c;
    // label cosine in f32 (exact margin/label terms later)
    int lab = labels[r];
    float4 wv = ((const float4*)(wgt + (size_t)lab * D_DIM))[lane];
    float dot = v.x * wv.x + v.y * wv.y + v.z * wv.z + v.w * wv.w;
    float ws = wv.x * wv.x + wv.y * wv.y + wv.z * wv.z + wv.w * wv.w;
    for (int m = 1; m < 64; m <<= 1) {
      dot += __shfl_xor(dot, m);
      ws += __shfl_xor(ws, m);
    }
    if (lane == 0) {
      lcos[r] = dot / sqrtf(ws);
      int p = atomicAdd(&cnt_i[lab], 1);
      if (p < 16) members[lab * 16 + p] = r;
    }
  } else {
    int wr_ = r - B_ROWS;
    if (wr_ >= C_CLS) {
      uchar4 z = {0, 0, 0, 0};
      ((uchar4*)(W8 + (size_t)wr_ * D_DIM))[lane] = z;
      return;
    }
    float4 v = ((const float4*)(wgt + (size_t)wr_ * D_DIM))[lane];
    float ss = v.x * v.x + v.y * v.y + v.z * v.z + v.w * v.w;
    for (int m = 1; m < 64; m <<= 1) ss += __shfl_xor(ss, m);
    float k = 1.0f / sqrtf(ss);
    uchar4 c;
    c.x = f32_to_e4m3(v.x * k); c.y = f32_to_e4m3(v.y * k);
    c.z = f32_to_e4m3(v.z * k); c.w = f32_to_e4m3(v.w * k);
    ((uchar4*)(W8 + (size_t)wr_ * D_DIM))[lane] = c;
  }
}

// ---- MX-fp8 cosine GEMM + exp-sum; M=256/N=128, R6/R7 DMA double-buffer ----
// grid (16 row-tiles, 32 splits), 256 thr = 4 row-waves of 64 rows x 128 cols.
// K-loop: 16x16x128 scaled MFMA (unit scales) -> 2 MFMAs per (mt,nt), 2x rate.
__global__ __launch_bounds__(256, 2) void gemm_softmax(
    const u8* __restrict__ E8, const u8* __restrict__ W8,
    float* __restrict__ row_S) {
  __shared__ char lds[65536];   // 2 x 32 KB
  const int tid = threadIdx.x;
  const int lane = tid & 63, w = tid >> 6;
  const int quad = lane >> 4, c16 = lane & 15;
  const int rt = blockIdx.x, sp = blockIdx.y;
  const int wr = w * 64;   // 4 waves x 64 rows = 256 rows

  // staging: granule g=i*256+tid -> row n=g>>4, slot g&15 holds src chunk (g&15)^(n&15)
  const int stageSrc = ((tid >> 4) << 8) + (((tid & 15) ^ (tid >> 4)) << 4);
  auto stage = [&](int buf, int t) {
    const char* src = (const char*)W8 + (size_t)t * 32768 + stageSrc;
    char* dst = lds + buf * 32768 + tid * 16;
#pragma unroll
    for (int i = 0; i < 8; ++i)
      __builtin_amdgcn_global_load_lds(
          (const __attribute__((address_space(1))) unsigned int*)(src + i * 4096),
          (__attribute__((address_space(3))) unsigned int*)(dst + i * 4096), 16, 0, 0);
  };

  stage(0, sp);   // prefetch first tile (async)

  // A fragments direct from global: row m=c16(+16mt+wr), k = kk*128 + quad*32 + byte
  intx8 a[4][2];
#pragma unroll
  for (int mt = 0; mt < 4; ++mt) {
    const u8* rp = E8 + ((size_t)(rt * 256 + wr + mt * 16 + c16)) * 256 + quad * 32;
#pragma unroll
    for (int kk = 0; kk < 2; ++kk)
      a[mt][kk] = *(const intx8*)(rp + kk * 128);
  }

  // B read offsets within a row: 32B chunk g=kk*8+quad*2 -> granules g,g+1 at slots ^c16
  int oA[2], oB[2];
#pragma unroll
  for (int kk = 0; kk < 2; ++kk) {
    oA[kk] = (((kk * 8 + quad * 2) ^ c16) << 4);
    oB[kk] = (((kk * 8 + quad * 2 + 1) ^ c16) << 4);
  }

  float run_s[4][4] = {};
  __syncthreads();   // first tile staged (barrier drains vmcnt)
  int cur = 0;
  for (int t = sp; t < NTILE; t += NSPLIT) {
    int tn = t + NSPLIT;
    if (tn < NTILE) stage(cur ^ 1, tn);   // in flight through the MFMA phase
    const char* bbase = lds + cur * 32768 + c16 * 256;
#pragma unroll
    for (int nt = 0; nt < 8; ++nt) {
      intx8 bv[2];
#pragma unroll
      for (int kk = 0; kk < 2; ++kk) {
        uint4 lo = *(const uint4*)(bbase + nt * 4096 + oA[kk]);
        uint4 hi = *(const uint4*)(bbase + nt * 4096 + oB[kk]);
        bv[kk][0] = (int)lo.x; bv[kk][1] = (int)lo.y;
        bv[kk][2] = (int)lo.z; bv[kk][3] = (int)lo.w;
        bv[kk][4] = (int)hi.x; bv[kk][5] = (int)hi.y;
        bv[kk][6] = (int)hi.z; bv[kk][7] = (int)hi.w;
      }
      floatx4 acc[4] = {};
#pragma unroll
      for (int kk = 0; kk < 2; ++kk)
#pragma unroll
        for (int mt = 0; mt < 4; ++mt)
          acc[mt] = __builtin_amdgcn_mfma_scale_f32_16x16x128_f8f6f4(
              a[mt][kk], bv[kk], acc[mt], 0, 0, 0, SCL1, 0, SCL1);
#pragma unroll
      for (int mt = 0; mt < 4; ++mt)
#pragma unroll
        for (int rg = 0; rg < 4; ++rg)
          run_s[mt][rg] += __builtin_amdgcn_exp2f(fmaf(SC, acc[mt][rg], -SC));
    }
    __syncthreads();   // waves done reading cur; prefetch into cur^1 drained
    cur ^= 1;
  }
  // reduce across 16 column lanes, one atomic per row per wave
#pragma unroll
  for (int mt = 0; mt < 4; ++mt)
#pragma unroll
    for (int rg = 0; rg < 4; ++rg) {
      float s = run_s[mt][rg];
      s += __shfl_xor(s, 1);
      s += __shfl_xor(s, 2);
      s += __shfl_xor(s, 4);
      s += __shfl_xor(s, 8);
      if (c16 == 0)
        atomicAdd(&row_S[rt * 256 + wr + mt * 16 + quad * 4 + rg], s);
    }
}

// ---- tail: intra loss (closed form, wave-per-class) + AM row terms,
//      block-level LDS reduction -> 3 atomics/block, ticket combine ----
__global__ __launch_bounds__(1024) void tail(
    const int* __restrict__ cnt_i, const int* __restrict__ members,
    const float* __restrict__ En, const float* __restrict__ row_S,
    const float* __restrict__ lcos, float* __restrict__ pgnv,
    float* __restrict__ out) {
  __shared__ float red[1024];
  const int t = threadIdx.x, blk = blockIdx.x;
  const int gtid = blk * 1024 + t;
  const int lane = t & 63;
  const int gw = gtid >> 6;   // global wave id, 0..1023

  // --- intra: each wave scans classes gw, gw+1024, ... (closed form) ---
  float pg = 0.0f, nv = 0.0f;
  for (int c = gw; c < C_CLS; c += 1024) {
    int m = cnt_i[c];                 // same addr across wave -> broadcast
    if (m < 2) continue;
    if (m > 16) m = 16;
    float4 S = {0.0f, 0.0f, 0.0f, 0.0f};
    for (int r = 0; r < m; ++r) {
      int row = members[c * 16 + r];
      float4 v = ((const float4*)(En + (size_t)row * D_DIM))[lane];
      S.x += v.x; S.y += v.y; S.z += v.z; S.w += v.w;
    }
    float ss = S.x * S.x + S.y * S.y + S.z * S.z + S.w * S.w;
    for (int k = 1; k < 64; k <<= 1) ss += __shfl_xor(ss, k);
    if (lane == 0) {
      // sum_{r<s}(1 - e_r.e_s) = C(m,2) - (|sum e|^2 - m)/2  (unit-norm rows)
      float fm = (float)m;
      float np = 0.5f * fm * (fm - 1.0f);
      float dsum = np - 0.5f * (ss - fm);
      pg += fmaxf(dsum / np - 0.5f, 0.0f);
      nv += 1.0f;
    }
  }

  // --- AM: thread-per-row (65536 threads cover 4096 rows) ---
  const float padc = 96.0f * __builtin_amdgcn_exp2f(-SC);  // pad classes: cos==0 exactly
  float nlp = 0.0f;
  for (int r = gtid; r < B_ROWS; r += TAIL_BLOCKS * 1024) {
    float c = lcos[r];
    float S = row_S[r] - padc
            + __builtin_amdgcn_exp2f(fmaf(SC, c, -SC - M9))   // margined label term
            - __builtin_amdgcn_exp2f(fmaf(SC, c, -SC));       // remove unmargined label term
    nlp += 30.0f + logf(S) - fmaf(30.0f, c, -9.0f);
  }

  // --- block reduce (pg, nv, nlp) -> 3 atomics per block ---
  float bsum[3];
  float vals[3] = {pg, nv, nlp};
#pragma unroll
  for (int q = 0; q < 3; ++q) {
    red[t] = vals[q];
    __syncthreads();
    for (int s = 512; s > 0; s >>= 1) {
      if (t < s) red[t] += red[t + s];
      __syncthreads();
    }
    bsum[q] = red[0];
    __syncthreads();
  }
  if (t == 0) {
    atomicAdd(&pgnv[0], bsum[0]);
    atomicAdd(&pgnv[1], bsum[1]);
    atomicAdd(&pgnv[2], bsum[2]);
    __threadfence();
    unsigned ticket = atomicAdd((unsigned*)&pgnv[3], 1u);
    if (ticket == TAIL_BLOCKS - 1) {   // last block: all adds device-visible
      float pgT = atomicAdd(&pgnv[0], 0.0f);
      float nvT = atomicAdd(&pgnv[1], 0.0f);
      float nlT = atomicAdd(&pgnv[2], 0.0f);
      float am = nlT * (1.0f / (float)B_ROWS);
      float intra = (nvT > 0.0f) ? (pgT / nvT) : 0.0f;
      out[0] = am + 0.1f * intra;
      out[1] = am;
      out[2] = intra;
    }
  }
}

extern "C" void kernel_launch(void* const* d_in, const int* in_sizes, int n_in,
                              void* d_out, int out_size, void* d_ws, size_t ws_size,
                              hipStream_t stream) {
  const float* emb = (const float*)d_in[0];
  const int* labels = (const int*)d_in[1];
  const float* weight = (const float*)d_in[2];
  float* out = (float*)d_out;
  char* ws = (char*)d_ws;

  float* En      = (float*)(ws);               // 4,194,304
  u8*    E8      = (u8*)(ws + 4194304);        // 1,048,576 -> 5,242,880
  u8*    W8      = (u8*)(ws + 5242880);        // 5,144,576 -> 10,387,456
  float* row_S   = (float*)(ws + 10387456);    //    16,384 -> 10,403,840
  int*   cnt_i   = (int*)(ws + 10403840);      //    80,000 -> 10,483,840
  float* pgnv    = (float*)(ws + 10483840);    //        16 -> 10,483,856
  float* lcos    = (float*)(ws + 10483856);    //    16,384 -> 10,500,240
  int*   members = (int*)(ws + 10500240);      // 1,280,000 -> 11,780,240

  hipMemsetAsync(ws + 10387456, 0, 96400, stream);  // row_S + cnt_i + pgnv(+ticket)
  normalize_all<<<(B_ROWS + C_PAD) / 4, 256, 0, stream>>>(emb, weight, labels, En, E8, W8,
                                                          lcos, cnt_i, members);
  gemm_softmax<<<dim3(16, NSPLIT), 256, 0, stream>>>(E8, W8, row_S);
  tail<<<TAIL_BLOCKS, 1024, 0, stream>>>(cnt_i, members, En, row_S, lcos, pgnv, out);
}

// Round 13
// 120.689 us; speedup vs baseline: 1.4602x; 1.0017x over previous
//
#include <hip/hip_runtime.h>
#include <math.h>

typedef unsigned char u8;
typedef __attribute__((ext_vector_type(4))) float floatx4;
typedef __attribute__((ext_vector_type(8))) int intx8;

#define B_ROWS 4096
#define D_DIM  256
#define C_CLS  20000
#define C_PAD  20096      // 157 tiles * 128
#define NTILE  157
#define NSPLIT 32
#define TAIL_BLOCKS 64

#define SC  43.280851227f   // 30 * log2(e)
#define M9  12.984255369f   // 9 * log2(e)
#define SCL1 0x7f7f7f7f     // e8m0 == 127 -> scale 2^0 = 1.0 (all bytes)

// ---- RNE f32 -> OCP e4m3fn (|v| <= 1 here; handles subnormals) ----
__device__ __forceinline__ u8 f32_to_e4m3(float v) {
  unsigned u = __float_as_uint(v);
  unsigned s = (u >> 24) & 0x80u;
  float a = fabsf(v);
  if (a < 0.0009765625f) return (u8)s;           // < 2^-10 -> rounds to 0
  unsigned ua = __float_as_uint(a);
  int ex = (int)(ua >> 23);
  if (ex < 121) ex = 121;                        // subnormal regime: step 2^-9
  float inv_step = __uint_as_float((unsigned)(257 - ex) << 23);  // 2^(3-e)
  float stepf    = __uint_as_float((unsigned)(ex - 3) << 23);    // 2^(e-3)
  float r = rintf(a * inv_step) * stepf;         // RNE to 3-bit mantissa grid
  unsigned code;
  if (r == 0.0f) code = 0;
  else {
    unsigned ur = __float_as_uint(r);
    int er = (int)(ur >> 23) - 127;
    if (er < -6) code = (unsigned)(r * 512.0f);  // subnormal: m * 2^-9
    else code = ((unsigned)(er + 7) << 3) | ((ur >> 20) & 7u);
  }
  return (u8)(s | code);
}

// ---- fused: normalize embeddings (f32+fp8) + label cosine + bucket; weights (fp8) ----
__global__ void normalize_all(const float* __restrict__ emb, const float* __restrict__ wgt,
                              const int* __restrict__ labels,
                              float* __restrict__ En, u8* __restrict__ E8,
                              u8* __restrict__ W8, float* __restrict__ lcos,
                              int* __restrict__ cnt_i, int* __restrict__ members) {
  const int r = blockIdx.x * 4 + (threadIdx.x >> 6);
  const int lane = threadIdx.x & 63;
  if (r < B_ROWS) {
    float4 v = ((const float4*)(emb + (size_t)r * D_DIM))[lane];
    float ss = v.x * v.x + v.y * v.y + v.z * v.z + v.w * v.w;
    for (int m = 1; m < 64; m <<= 1) ss += __shfl_xor(ss, m);
    float k = 1.0f / sqrtf(ss);
    v.x *= k; v.y *= k; v.z *= k; v.w *= k;
    ((float4*)(En + (size_t)r * D_DIM))[lane] = v;
    uchar4 c;
    c.x = f32_to_e4m3(v.x); c.y = f32_to_e4m3(v.y);
    c.z = f32_to_e4m3(v.z); c.w = f32_to_e4m3(v.w);
    ((uchar4*)(E8 + (size_t)r * D_DIM))[lane] = c;
    // label cosine in f32 (exact margin/label terms later)
    int lab = labels[r];
    float4 wv = ((const float4*)(wgt + (size_t)lab * D_DIM))[lane];
    float dot = v.x * wv.x + v.y * wv.y + v.z * wv.z + v.w * wv.w;
    float ws = wv.x * wv.x + wv.y * wv.y + wv.z * wv.z + wv.w * wv.w;
    for (int m = 1; m < 64; m <<= 1) {
      dot += __shfl_xor(dot, m);
      ws += __shfl_xor(ws, m);
    }
    if (lane == 0) {
      lcos[r] = dot / sqrtf(ws);
      int p = atomicAdd(&cnt_i[lab], 1);
      if (p < 16) members[lab * 16 + p] = r;
    }
  } else {
    int wr_ = r - B_ROWS;
    if (wr_ >= C_CLS) {
      uchar4 z = {0, 0, 0, 0};
      ((uchar4*)(W8 + (size_t)wr_ * D_DIM))[lane] = z;
      return;
    }
    float4 v = ((const float4*)(wgt + (size_t)wr_ * D_DIM))[lane];
    float ss = v.x * v.x + v.y * v.y + v.z * v.z + v.w * v.w;
    for (int m = 1; m < 64; m <<= 1) ss += __shfl_xor(ss, m);
    float k = 1.0f / sqrtf(ss);
    uchar4 c;
    c.x = f32_to_e4m3(v.x * k); c.y = f32_to_e4m3(v.y * k);
    c.z = f32_to_e4m3(v.z * k); c.w = f32_to_e4m3(v.w * k);
    ((uchar4*)(W8 + (size_t)wr_ * D_DIM))[lane] = c;
  }
}

// ---- MX-fp8 cosine GEMM + exp-sum; M=256/N=128, DMA double-buffer (R11) ----
// grid (16 row-tiles, 32 splits), 256 thr = 4 row-waves of 64 rows x 128 cols.
// K-loop: 16x16x128 scaled MFMA (unit scales) -> 2 MFMAs per (mt,nt), 2x rate.
// Output: plain stores into per-split slab row_S2[sp][row] (no atomics, no zeroing).
__global__ __launch_bounds__(256, 2) void gemm_softmax(
    const u8* __restrict__ E8, const u8* __restrict__ W8,
    float* __restrict__ row_S2) {
  __shared__ char lds[65536];   // 2 x 32 KB
  const int tid = threadIdx.x;
  const int lane = tid & 63, w = tid >> 6;
  const int quad = lane >> 4, c16 = lane & 15;
  const int rt = blockIdx.x, sp = blockIdx.y;
  const int wr = w * 64;   // 4 waves x 64 rows = 256 rows

  // staging: granule g=i*256+tid -> row n=g>>4, slot g&15 holds src chunk (g&15)^(n&15)
  const int stageSrc = ((tid >> 4) << 8) + (((tid & 15) ^ (tid >> 4)) << 4);
  auto stage = [&](int buf, int t) {
    const char* src = (const char*)W8 + (size_t)t * 32768 + stageSrc;
    char* dst = lds + buf * 32768 + tid * 16;
#pragma unroll
    for (int i = 0; i < 8; ++i)
      __builtin_amdgcn_global_load_lds(
          (const __attribute__((address_space(1))) unsigned int*)(src + i * 4096),
          (__attribute__((address_space(3))) unsigned int*)(dst + i * 4096), 16, 0, 0);
  };

  stage(0, sp);   // prefetch first tile (async)

  // A fragments direct from global: row m=c16(+16mt+wr), k = kk*128 + quad*32 + byte
  intx8 a[4][2];
#pragma unroll
  for (int mt = 0; mt < 4; ++mt) {
    const u8* rp = E8 + ((size_t)(rt * 256 + wr + mt * 16 + c16)) * 256 + quad * 32;
#pragma unroll
    for (int kk = 0; kk < 2; ++kk)
      a[mt][kk] = *(const intx8*)(rp + kk * 128);
  }

  // B read offsets within a row: 32B chunk g=kk*8+quad*2 -> granules g,g+1 at slots ^c16
  int oA[2], oB[2];
#pragma unroll
  for (int kk = 0; kk < 2; ++kk) {
    oA[kk] = (((kk * 8 + quad * 2) ^ c16) << 4);
    oB[kk] = (((kk * 8 + quad * 2 + 1) ^ c16) << 4);
  }

  float run_s[4][4] = {};
  __syncthreads();   // first tile staged (barrier drains vmcnt)
  int cur = 0;
  for (int t = sp; t < NTILE; t += NSPLIT) {
    int tn = t + NSPLIT;
    if (tn < NTILE) stage(cur ^ 1, tn);   // in flight through the MFMA phase
    const char* bbase = lds + cur * 32768 + c16 * 256;
#pragma unroll
    for (int nt = 0; nt < 8; ++nt) {
      intx8 bv[2];
#pragma unroll
      for (int kk = 0; kk < 2; ++kk) {
        uint4 lo = *(const uint4*)(bbase + nt * 4096 + oA[kk]);
        uint4 hi = *(const uint4*)(bbase + nt * 4096 + oB[kk]);
        bv[kk][0] = (int)lo.x; bv[kk][1] = (int)lo.y;
        bv[kk][2] = (int)lo.z; bv[kk][3] = (int)lo.w;
        bv[kk][4] = (int)hi.x; bv[kk][5] = (int)hi.y;
        bv[kk][6] = (int)hi.z; bv[kk][7] = (int)hi.w;
      }
      floatx4 acc[4] = {};
#pragma unroll
      for (int kk = 0; kk < 2; ++kk)
#pragma unroll
        for (int mt = 0; mt < 4; ++mt)
          acc[mt] = __builtin_amdgcn_mfma_scale_f32_16x16x128_f8f6f4(
              a[mt][kk], bv[kk], acc[mt], 0, 0, 0, SCL1, 0, SCL1);
#pragma unroll
      for (int mt = 0; mt < 4; ++mt)
#pragma unroll
        for (int rg = 0; rg < 4; ++rg)
          run_s[mt][rg] += __builtin_amdgcn_exp2f(fmaf(SC, acc[mt][rg], -SC));
    }
    __syncthreads();   // waves done reading cur; prefetch into cur^1 drained
    cur ^= 1;
  }
  // reduce across 16 column lanes; plain store into per-split slab
#pragma unroll
  for (int mt = 0; mt < 4; ++mt)
#pragma unroll
    for (int rg = 0; rg < 4; ++rg) {
      float s = run_s[mt][rg];
      s += __shfl_xor(s, 1);
      s += __shfl_xor(s, 2);
      s += __shfl_xor(s, 4);
      s += __shfl_xor(s, 8);
      if (c16 == 0)
        row_S2[sp * B_ROWS + rt * 256 + wr + mt * 16 + quad * 4 + rg] = s;
    }
}

// ---- tail: intra loss (closed form, wave-per-class) + AM row terms,
//      block-level LDS reduction -> 3 atomics/block, ticket combine ----
__global__ __launch_bounds__(1024) void tail(
    const int* __restrict__ cnt_i, const int* __restrict__ members,
    const float* __restrict__ En, const float* __restrict__ row_S2,
    const float* __restrict__ lcos, float* __restrict__ pgnv,
    float* __restrict__ out) {
  __shared__ float red[1024];
  const int t = threadIdx.x, blk = blockIdx.x;
  const int gtid = blk * 1024 + t;
  const int lane = t & 63;
  const int gw = gtid >> 6;   // global wave id, 0..1023

  // --- intra: each wave scans classes gw, gw+1024, ... (closed form) ---
  float pg = 0.0f, nv = 0.0f;
  for (int c = gw; c < C_CLS; c += 1024) {
    int m = cnt_i[c];                 // same addr across wave -> broadcast
    if (m < 2) continue;
    if (m > 16) m = 16;
    float4 S = {0.0f, 0.0f, 0.0f, 0.0f};
    for (int r = 0; r < m; ++r) {
      int row = members[c * 16 + r];
      float4 v = ((const float4*)(En + (size_t)row * D_DIM))[lane];
      S.x += v.x; S.y += v.y; S.z += v.z; S.w += v.w;
    }
    float ss = S.x * S.x + S.y * S.y + S.z * S.z + S.w * S.w;
    for (int k = 1; k < 64; k <<= 1) ss += __shfl_xor(ss, k);
    if (lane == 0) {
      // sum_{r<s}(1 - e_r.e_s) = C(m,2) - (|sum e|^2 - m)/2  (unit-norm rows)
      float fm = (float)m;
      float np = 0.5f * fm * (fm - 1.0f);
      float dsum = np - 0.5f * (ss - fm);
      pg += fmaxf(dsum / np - 0.5f, 0.0f);
      nv += 1.0f;
    }
  }

  // --- AM: thread-per-row; sum the 32 per-split slabs ---
  const float padc = 96.0f * __builtin_amdgcn_exp2f(-SC);  // pad classes: cos==0 exactly
  float nlp = 0.0f;
  for (int r = gtid; r < B_ROWS; r += TAIL_BLOCKS * 1024) {
    float Ssum = 0.0f;
#pragma unroll 8
    for (int s = 0; s < NSPLIT; ++s) Ssum += row_S2[s * B_ROWS + r];
    float c = lcos[r];
    float S = Ssum - padc
            + __builtin_amdgcn_exp2f(fmaf(SC, c, -SC - M9))   // margined label term
            - __builtin_amdgcn_exp2f(fmaf(SC, c, -SC));       // remove unmargined label term
    nlp += 30.0f + logf(S) - fmaf(30.0f, c, -9.0f);
  }

  // --- block reduce (pg, nv, nlp) -> 3 atomics per block ---
  float bsum[3];
  float vals[3] = {pg, nv, nlp};
#pragma unroll
  for (int q = 0; q < 3; ++q) {
    red[t] = vals[q];
    __syncthreads();
    for (int s = 512; s > 0; s >>= 1) {
      if (t < s) red[t] += red[t + s];
      __syncthreads();
    }
    bsum[q] = red[0];
    __syncthreads();
  }
  if (t == 0) {
    atomicAdd(&pgnv[0], bsum[0]);
    atomicAdd(&pgnv[1], bsum[1]);
    atomicAdd(&pgnv[2], bsum[2]);
    __threadfence();
    unsigned ticket = atomicAdd((unsigned*)&pgnv[3], 1u);
    if (ticket == TAIL_BLOCKS - 1) {   // last block: all adds device-visible
      float pgT = atomicAdd(&pgnv[0], 0.0f);
      float nvT = atomicAdd(&pgnv[1], 0.0f);
      float nlT = atomicAdd(&pgnv[2], 0.0f);
      float am = nlT * (1.0f / (float)B_ROWS);
      float intra = (nvT > 0.0f) ? (pgT / nvT) : 0.0f;
      out[0] = am + 0.1f * intra;
      out[1] = am;
      out[2] = intra;
    }
  }
}

extern "C" void kernel_launch(void* const* d_in, const int* in_sizes, int n_in,
                              void* d_out, int out_size, void* d_ws, size_t ws_size,
                              hipStream_t stream) {
  const float* emb = (const float*)d_in[0];
  const int* labels = (const int*)d_in[1];
  const float* weight = (const float*)d_in[2];
  float* out = (float*)d_out;
  char* ws = (char*)d_ws;

  float* En      = (float*)(ws);               // 4,194,304
  u8*    E8      = (u8*)(ws + 4194304);        // 1,048,576 -> 5,242,880
  u8*    W8      = (u8*)(ws + 5242880);        // 5,144,576 -> 10,387,456
  float* row_S2  = (float*)(ws + 10387456);    //   524,288 -> 10,911,744 (no zeroing)
  int*   cnt_i   = (int*)(ws + 10911744);      //    80,000 -> 10,991,744
  float* pgnv    = (float*)(ws + 10991744);    //        16 -> 10,991,760
  float* lcos    = (float*)(ws + 10991760);    //    16,384 -> 11,008,144
  int*   members = (int*)(ws + 11008144);      // 1,280,000 -> 12,288,144

  hipMemsetAsync(ws + 10911744, 0, 80016, stream);  // cnt_i + pgnv(+ticket)
  normalize_all<<<(B_ROWS + C_PAD) / 4, 256, 0, stream>>>(emb, weight, labels, En, E8, W8,
                                                          lcos, cnt_i, members);
  gemm_softmax<<<dim3(16, NSPLIT), 256, 0, stream>>>(E8, W8, row_S2);
  tail<<<TAIL_BLOCKS, 1024, 0, stream>>>(cnt_i, members, En, row_S2, lcos, pgnv, out);
}